// Round 13
// baseline (705.457 us; speedup 1.0000x reference)
//
#include <hip/hip_runtime.h>
#include <math.h>

#define NN 100000
#define NE 1600000
#define NB 782      // dst buckets of 128 nodes
#define BCAP 3072   // bucket capacity (mean ~2046, 22 sigma safe)
#define BKBLK 128   // blocks in bucket build
#define BKCHUNK (NE / BKBLK)  // 12500 edges per block
#define DBINS 64    // degree bins for counting sort

typedef unsigned short ushort_t;
typedef unsigned int uint_t;
typedef __attribute__((ext_vector_type(8))) short bf16x8;
typedef __attribute__((ext_vector_type(8))) unsigned short u16x8;
typedef __attribute__((ext_vector_type(4))) float f32x4;

__device__ __forceinline__ ushort_t f2bf(float f) {
  uint_t u = __float_as_uint(f);
  u = (u + 0x7fffu + ((u >> 16) & 1u)) >> 16;   // round-to-nearest-even
  return (ushort_t)u;
}
__device__ __forceinline__ float bf2f(ushort_t h) {
  return __uint_as_float((uint_t)h << 16);
}

// ---------------- setup: bucketed CSR build (histogram + reserve + write) ----------------

__global__ __launch_bounds__(512) void bucketA_k(const int* __restrict__ src, const int* __restrict__ dst,
                                                 int* __restrict__ bcnt, uint_t* __restrict__ pairs) {
  __shared__ int h[NB];
  const int t = threadIdx.x;
  const int e0 = blockIdx.x * BKCHUNK;
  for (int b = t; b < NB; b += 512) h[b] = 0;
  __syncthreads();
  for (int i = t; i < BKCHUNK; i += 512) atomicAdd(&h[dst[e0 + i] >> 7], 1);
  __syncthreads();
  for (int b = t; b < NB; b += 512) h[b] = atomicAdd(&bcnt[b], h[b]);
  __syncthreads();
  for (int i = t; i < BKCHUNK; i += 512) {
    int s = src[e0 + i], d = dst[e0 + i];
    int b = d >> 7;
    int pos = atomicAdd(&h[b], 1);
    if (pos < BCAP) pairs[b * BCAP + pos] = ((uint_t)s << 7) | (uint_t)(d & 127);
  }
}

// count + dinv + degree-histogram fused
__global__ __launch_bounds__(256) void count2_k(const int* __restrict__ bcnt, const uint_t* __restrict__ pairs,
                                                int* __restrict__ cnt, float* __restrict__ dinv,
                                                int* __restrict__ dbin) {
  __shared__ int c[128];
  __shared__ int hb[DBINS];
  int b = blockIdx.x, t = threadIdx.x;
  if (t < 128) c[t] = 0;
  if (t >= 128 && t < 128 + DBINS) hb[t - 128] = 0;
  __syncthreads();
  int n = min(bcnt[b], BCAP);
  for (int i = t; i < n; i += 256) atomicAdd(&c[pairs[b * BCAP + i] & 127], 1);
  __syncthreads();
  if (t < 128) {
    int node = b * 128 + t;
    if (node < NN) {
      int cc = c[t];
      cnt[node] = cc;
      dinv[node] = rsqrtf((float)(cc + 1));
      atomicAdd(&hb[min(cc, DBINS - 1)], 1);
    }
  }
  __syncthreads();
  if (t < DBINS && hb[t]) atomicAdd(&dbin[t], hb[t]);
}

__global__ __launch_bounds__(1024) void scan1(const int* __restrict__ cnt, int* __restrict__ rowstart,
                                              int* __restrict__ blocksum) {
  __shared__ int s[1024];
  int t = threadIdx.x;
  int i = blockIdx.x * 1024 + t;
  int v = (i < NN) ? cnt[i] : 0;
  s[t] = v;
  __syncthreads();
  for (int off = 1; off < 1024; off <<= 1) {
    int add = (t >= off) ? s[t - off] : 0;
    __syncthreads();
    s[t] += add;
    __syncthreads();
  }
  if (i < NN) rowstart[i] = s[t] - v;   // exclusive
  if (t == 1023) blocksum[blockIdx.x] = s[1023];
}

// blocksum scan + degree-bin scan fused
__global__ void scan2(int* blocksum, int nb, const int* __restrict__ dbin, int* __restrict__ dcur) {
  if (threadIdx.x == 0 && blockIdx.x == 0) {
    int acc = 0;
    for (int b = 0; b < nb; ++b) { int v = blocksum[b]; blocksum[b] = acc; acc += v; }
    int a2 = 0;
    for (int b = 0; b < DBINS; ++b) { dcur[b] = a2; a2 += dbin[b]; }
  }
}

__global__ __launch_bounds__(1024) void scan3(int* __restrict__ rowstart, const int* __restrict__ blocksum) {
  int i = blockIdx.x * 1024 + threadIdx.x;
  if (i < NN) rowstart[i] += blocksum[blockIdx.x];
}

// CSR fill (blocks 0..NB-1) + degree-sort placement (blocks NB..) fused
__global__ __launch_bounds__(256) void fillplace_k(const int* __restrict__ bcnt, const uint_t* __restrict__ pairs,
                                                   const int* __restrict__ rowstart, int* __restrict__ csr,
                                                   const int* __restrict__ cnt, int* __restrict__ dcur,
                                                   int* __restrict__ perm) {
  int t = threadIdx.x;
  if (blockIdx.x < NB) {
    __shared__ int cur[128];
    int b = blockIdx.x;
    if (t < 128) cur[t] = 0;
    __syncthreads();
    int n = min(bcnt[b], BCAP);
    for (int i = t; i < n; i += 256) {
      uint_t p = pairs[b * BCAP + i];
      int lo = p & 127;
      int pos = rowstart[b * 128 + lo] + atomicAdd(&cur[lo], 1);
      csr[pos] = (int)(p >> 7);
    }
  } else {
    __shared__ int h[DBINS];
    __shared__ int lbase[DBINS];
    int i = (blockIdx.x - NB) * 256 + t;
    if (t < DBINS) h[t] = 0;
    __syncthreads();
    int bin = 0, lrank = 0;
    if (i < NN) { bin = min(cnt[i], DBINS - 1); lrank = atomicAdd(&h[bin], 1); }
    __syncthreads();
    if (t < DBINS) lbase[t] = h[t] ? atomicAdd(&dcur[t], h[t]) : 0;
    __syncthreads();
    if (i < NN) perm[lbase[bin] + lrank] = i;
  }
}

// ---------------- weight prep (transpose + split) and tail composition, fused ----------------

__global__ __launch_bounds__(256) void wcprep_k(const float* __restrict__ Wg1, const float* __restrict__ Wl,
                                                const float* __restrict__ W2, const float* __restrict__ Wf,
                                                const float* __restrict__ b2, const float* __restrict__ b9,
                                                const float* __restrict__ bfb,
                                                ushort_t* __restrict__ G1h, ushort_t* __restrict__ G1l,
                                                ushort_t* __restrict__ Lh, ushort_t* __restrict__ Ll,
                                                ushort_t* __restrict__ Fh, ushort_t* __restrict__ Fl,
                                                float* __restrict__ bc) {
  if (blockIdx.x < 224) {   // wprep: Wg1 + Wl
    int i = blockIdx.x * 256 + threadIdx.x;   // 0..57343
    if (i >= 57344) return;
    float w;
    ushort_t *ph, *pl;
    size_t di;
    if (i < 16384) {           // Wg1 128x128
      int k = i >> 7, n = i & 127;
      w = Wg1[i]; di = (size_t)n * 128 + k; ph = G1h; pl = G1l;
    } else {                   // Wl 10 x 64x64
      int i2 = i - 16384;
      int j = i2 >> 12, r = i2 & 4095;
      int k = r >> 6, n = r & 63;
      w = Wl[i2]; di = (size_t)j * 4096 + n * 64 + k; ph = Lh; pl = Ll;
    }
    ushort_t h = f2bf(w);
    ph[di] = h;
    pl[di] = f2bf(w - bf2f(h));
  } else {                  // ccomp: Wc = [W2*Wf1 ; W9*Wf2], bc
    const float* W9 = Wl + (size_t)9 * 4096;
    int i = (blockIdx.x - 224) * 256 + threadIdx.x;   // 0..12287
    if (i >= 12288) return;
    int k = i >> 6, n = i & 63;
    float acc = 0.0f;
    if (k < 128) {
      for (int j = 0; j < 128; ++j) acc += W2[k * 128 + j] * Wf[j * 64 + n];
    } else {
      int k2 = k - 128;
      for (int j = 0; j < 64; ++j) acc += W9[k2 * 64 + j] * Wf[(128 + j) * 64 + n];
    }
    ushort_t h = f2bf(acc);
    Fh[(size_t)n * 192 + k] = h;
    Fl[(size_t)n * 192 + k] = f2bf(acc - bf2f(h));
    if (k == 0) {
      float b = bfb[n];
      for (int j = 0; j < 128; ++j) b += b2[j] * Wf[j * 64 + n];
      for (int j = 0; j < 64; ++j) b += b9[j] * Wf[(128 + j) * 64 + n];
      bc[n] = b;
    }
  }
}

// ---------------- conv1 MFMA GEMM (K=128, chunked LDS staging, bf16x3, proven) ----------------

template <int K, int DC>
__global__ __launch_bounds__(256) void mgemm_k(const float* __restrict__ A,
                                               const ushort_t* __restrict__ Wth, const ushort_t* __restrict__ Wtl,
                                               const float* __restrict__ dinv, ushort_t* __restrict__ C) {
  constexpr int NCH = K / 64;
  __shared__ ushort_t Ah[64 * 64], Al[64 * 64];
  __shared__ ushort_t Wh[DC * 64], Wl_[DC * 64];
  const int t = threadIdx.x;
  const int row0 = blockIdx.x * 64;
  const int w = t >> 6, l = t & 63;
  const int lr = l & 15, kh = l >> 4;

  f32x4 acc[DC / 16];
  const f32x4 zz = {0.f, 0.f, 0.f, 0.f};
#pragma unroll
  for (int ct = 0; ct < DC / 16; ++ct) acc[ct] = zz;

  for (int kc = 0; kc < NCH; ++kc) {
    if (kc) __syncthreads();
#pragma unroll
    for (int it = 0; it < 4; ++it) {
      int idx = t + it * 256;
      int row = idx >> 4, kq = idx & 15;
      int gr = min(row0 + row, NN - 1);
      float4 a = *(const float4*)&A[(size_t)gr * K + kc * 64 + kq * 4];
      ushort4 h, lo;
      h.x = f2bf(a.x); lo.x = f2bf(a.x - bf2f(h.x));
      h.y = f2bf(a.y); lo.y = f2bf(a.y - bf2f(h.y));
      h.z = f2bf(a.z); lo.z = f2bf(a.z - bf2f(h.z));
      h.w = f2bf(a.w); lo.w = f2bf(a.w - bf2f(h.w));
      int byt = (row * 128 + kq * 8) ^ ((row & 7) << 4);
      *(ushort4*)&Ah[byt >> 1] = h;
      *(ushort4*)&Al[byt >> 1] = lo;
    }
    for (int idx = t; idx < DC * 8; idx += 256) {
      int n = idx >> 3, kq = idx & 7;
      u16x8 hv = *(const u16x8*)&Wth[(size_t)n * K + kc * 64 + kq * 8];
      u16x8 lv = *(const u16x8*)&Wtl[(size_t)n * K + kc * 64 + kq * 8];
      int byt = (n * 128 + kq * 16) ^ ((n & 7) << 4);
      *(u16x8*)&Wh[byt >> 1] = hv;
      *(u16x8*)&Wl_[byt >> 1] = lv;
    }
    __syncthreads();
#pragma unroll
    for (int kc2 = 0; kc2 < 2; ++kc2) {
      int arow = w * 16 + lr;
      int ab = (arow * 128 + kc2 * 64 + kh * 16) ^ ((arow & 7) << 4);
      bf16x8 ah = *(const bf16x8*)&Ah[ab >> 1];
      bf16x8 al = *(const bf16x8*)&Al[ab >> 1];
#pragma unroll
      for (int ct = 0; ct < DC / 16; ++ct) {
        int n = ct * 16 + lr;
        int bb = (n * 128 + kc2 * 64 + kh * 16) ^ ((n & 7) << 4);
        bf16x8 bh = *(const bf16x8*)&Wh[bb >> 1];
        bf16x8 bl = *(const bf16x8*)&Wl_[bb >> 1];
        acc[ct] = __builtin_amdgcn_mfma_f32_16x16x32_bf16(al, bh, acc[ct], 0, 0, 0);
        acc[ct] = __builtin_amdgcn_mfma_f32_16x16x32_bf16(ah, bl, acc[ct], 0, 0, 0);
        acc[ct] = __builtin_amdgcn_mfma_f32_16x16x32_bf16(ah, bh, acc[ct], 0, 0, 0);
      }
    }
  }
  float dv[4];
#pragma unroll
  for (int r = 0; r < 4; ++r) {
    int grow = row0 + w * 16 + kh * 4 + r;
    dv[r] = (grow < NN) ? dinv[grow] : 0.0f;
  }
#pragma unroll
  for (int ct = 0; ct < DC / 16; ++ct) {
    int col = ct * 16 + lr;
#pragma unroll
    for (int r = 0; r < 4; ++r) {
      int grow = row0 + w * 16 + kh * 4 + r;
      if (grow < NN) C[(size_t)grow * DC + col] = f2bf(acc[ct][r] * dv[r]);
    }
  }
}

// ---------------- W-resident MFMA GEMM (label-chain start): W in LDS once, A global->reg ----------------

template <int K1, int K2, int DC, bool AF32>
__global__ __launch_bounds__(256) void mgemmW_k(const void* __restrict__ A1v, const void* __restrict__ A2v,
                                                const ushort_t* __restrict__ Wth, const ushort_t* __restrict__ Wtl,
                                                const float* __restrict__ dinv, ushort_t* __restrict__ C) {
  constexpr int K = K1 + K2;
  __shared__ ushort_t Wh[DC * K], Wl_[DC * K];
  const int t = threadIdx.x;
  const int w = t >> 6, l = t & 63;
  const int lr = l & 15, kh = l >> 4;
  const int row0 = blockIdx.x * 64;
  const int arow = min(row0 + w * 16 + lr, NN - 1);

  for (int idx = t; idx < DC * (K / 8); idx += 256) {
    int n = idx / (K / 8), kq = idx % (K / 8);
    u16x8 hv = *(const u16x8*)&Wth[(size_t)n * K + kq * 8];
    u16x8 lv = *(const u16x8*)&Wtl[(size_t)n * K + kq * 8];
    int byt = (n * K * 2 + kq * 16) ^ ((n & 7) << 4);
    *(u16x8*)&Wh[byt >> 1] = hv;
    *(u16x8*)&Wl_[byt >> 1] = lv;
  }
  __syncthreads();

  f32x4 acc[DC / 16];
  const f32x4 zz = {0.f, 0.f, 0.f, 0.f};
#pragma unroll
  for (int ct = 0; ct < DC / 16; ++ct) acc[ct] = zz;

#pragma unroll
  for (int kc = 0; kc < K / 32; ++kc) {
    const int kbase = kc * 32 + kh * 8;
    bf16x8 ah, al;
    if constexpr (AF32) {
      const float* Ap;
      if (K2 > 0 && kbase >= K1) Ap = &((const float*)A2v)[(size_t)arow * K2 + kbase - K1];
      else                       Ap = &((const float*)A1v)[(size_t)arow * K1 + kbase];
      float4 a0 = *(const float4*)Ap;
      float4 a1 = *(const float4*)(Ap + 4);
      float av[8] = {a0.x, a0.y, a0.z, a0.w, a1.x, a1.y, a1.z, a1.w};
      u16x8 hv, lv;
#pragma unroll
      for (int e = 0; e < 8; ++e) {
        ushort_t h = f2bf(av[e]);
        hv[e] = h;
        lv[e] = f2bf(av[e] - bf2f(h));
      }
      ah = (bf16x8)hv; al = (bf16x8)lv;
    } else {
      const ushort_t* Ap;
      if (K2 > 0 && kbase >= K1) Ap = &((const ushort_t*)A2v)[(size_t)arow * K2 + kbase - K1];
      else                       Ap = &((const ushort_t*)A1v)[(size_t)arow * K1 + kbase];
      ah = *(const bf16x8*)Ap;
    }
#pragma unroll
    for (int ct = 0; ct < DC / 16; ++ct) {
      const int n = ct * 16 + lr;
      const int bb = (n * K * 2 + kc * 64 + kh * 16) ^ ((n & 7) << 4);
      bf16x8 bh = *(const bf16x8*)&Wh[bb >> 1];
      bf16x8 bl = *(const bf16x8*)&Wl_[bb >> 1];
      if constexpr (AF32) acc[ct] = __builtin_amdgcn_mfma_f32_16x16x32_bf16(al, bh, acc[ct], 0, 0, 0);
      acc[ct] = __builtin_amdgcn_mfma_f32_16x16x32_bf16(ah, bl, acc[ct], 0, 0, 0);
      acc[ct] = __builtin_amdgcn_mfma_f32_16x16x32_bf16(ah, bh, acc[ct], 0, 0, 0);
    }
  }

  float dv[4];
#pragma unroll
  for (int r = 0; r < 4; ++r) {
    int grow = row0 + w * 16 + kh * 4 + r;
    dv[r] = (grow < NN) ? dinv[grow] : 0.0f;
  }
#pragma unroll
  for (int ct = 0; ct < DC / 16; ++ct) {
    int col = ct * 16 + lr;
#pragma unroll
    for (int r = 0; r < 4; ++r) {
      int grow = row0 + w * 16 + kh * 4 + r;
      if (grow < NN) C[(size_t)grow * DC + col] = f2bf(acc[ct][r] * dv[r]);
    }
  }
}

// ---------------- fused label layer: agg_j (gather) + GEMM_{j+1} (W-resident, P in regs) ----------------
// Gather: 8-edge two-phase unroll (8 outstanding uint4 per phase).

__global__ __launch_bounds__(256) void flay_k(const uint4* __restrict__ U,
                                              const ushort_t* __restrict__ Wth, const ushort_t* __restrict__ Wtl,
                                              const int* __restrict__ perm, const int* __restrict__ rowstart,
                                              const int* __restrict__ cnt, const int* __restrict__ csr,
                                              const float* __restrict__ dinv, const float* __restrict__ bias,
                                              ushort_t* __restrict__ Un) {
  __shared__ ushort_t Wh[64 * 64], Wl_[64 * 64];   // 16 KB
  const int t = threadIdx.x;
  for (int idx = t; idx < 64 * 8; idx += 256) {
    int n = idx >> 3, kq = idx & 7;
    u16x8 hv = *(const u16x8*)&Wth[(size_t)n * 64 + kq * 8];
    u16x8 lv = *(const u16x8*)&Wtl[(size_t)n * 64 + kq * 8];
    int byt = (n * 128 + kq * 16) ^ ((n & 7) << 4);
    *(u16x8*)&Wh[byt >> 1] = hv;
    *(u16x8*)&Wl_[byt >> 1] = lv;
  }
  __syncthreads();

  const int w = t >> 6, l = t & 63;
  const int lr = l & 15, kh = l >> 4;
  const int slot0 = blockIdx.x * 64 + w * 16;
  const int slot = min(slot0 + lr, NN - 1);
  const int node = perm[NN - 1 - slot];

  float acc[16];
  {
    uint4 a = U[(size_t)node * 8 + kh];
    uint4 b = U[(size_t)node * 8 + 4 + kh];
    uint_t ua[4] = {a.x, a.y, a.z, a.w};
    uint_t ub[4] = {b.x, b.y, b.z, b.w};
#pragma unroll
    for (int q = 0; q < 4; ++q) {
      acc[2 * q]      = __uint_as_float(ua[q] << 16);
      acc[2 * q + 1]  = __uint_as_float(ua[q] & 0xffff0000u);
      acc[8 + 2 * q]     = __uint_as_float(ub[q] << 16);
      acc[8 + 2 * q + 1] = __uint_as_float(ub[q] & 0xffff0000u);
    }
  }
  int s = rowstart[node], c = cnt[node];
  int j = 0;
  for (; j + 8 <= c; j += 8) {
    int idx[8];
#pragma unroll
    for (int u = 0; u < 8; ++u) idx[u] = csr[s + j + u];
    uint4 v[8];
#pragma unroll
    for (int u = 0; u < 8; ++u) v[u] = U[(size_t)idx[u] * 8 + kh];
#pragma unroll
    for (int u = 0; u < 8; ++u) {
      uint_t a0 = v[u].x, a1 = v[u].y, a2 = v[u].z, a3 = v[u].w;
      acc[0] += __uint_as_float(a0 << 16); acc[1] += __uint_as_float(a0 & 0xffff0000u);
      acc[2] += __uint_as_float(a1 << 16); acc[3] += __uint_as_float(a1 & 0xffff0000u);
      acc[4] += __uint_as_float(a2 << 16); acc[5] += __uint_as_float(a2 & 0xffff0000u);
      acc[6] += __uint_as_float(a3 << 16); acc[7] += __uint_as_float(a3 & 0xffff0000u);
    }
#pragma unroll
    for (int u = 0; u < 8; ++u) v[u] = U[(size_t)idx[u] * 8 + 4 + kh];
#pragma unroll
    for (int u = 0; u < 8; ++u) {
      uint_t b0 = v[u].x, b1 = v[u].y, b2 = v[u].z, b3 = v[u].w;
      acc[8]  += __uint_as_float(b0 << 16); acc[9]  += __uint_as_float(b0 & 0xffff0000u);
      acc[10] += __uint_as_float(b1 << 16); acc[11] += __uint_as_float(b1 & 0xffff0000u);
      acc[12] += __uint_as_float(b2 << 16); acc[13] += __uint_as_float(b2 & 0xffff0000u);
      acc[14] += __uint_as_float(b3 << 16); acc[15] += __uint_as_float(b3 & 0xffff0000u);
    }
  }
  for (; j < c; ++j) {
    int sn = csr[s + j];
    uint4 a = U[(size_t)sn * 8 + kh];
    uint4 b = U[(size_t)sn * 8 + 4 + kh];
    uint_t a0 = a.x, a1 = a.y, a2 = a.z, a3 = a.w;
    uint_t b0 = b.x, b1 = b.y, b2 = b.z, b3 = b.w;
    acc[0] += __uint_as_float(a0 << 16); acc[1] += __uint_as_float(a0 & 0xffff0000u);
    acc[2] += __uint_as_float(a1 << 16); acc[3] += __uint_as_float(a1 & 0xffff0000u);
    acc[4] += __uint_as_float(a2 << 16); acc[5] += __uint_as_float(a2 & 0xffff0000u);
    acc[6] += __uint_as_float(a3 << 16); acc[7] += __uint_as_float(a3 & 0xffff0000u);
    acc[8]  += __uint_as_float(b0 << 16); acc[9]  += __uint_as_float(b0 & 0xffff0000u);
    acc[10] += __uint_as_float(b1 << 16); acc[11] += __uint_as_float(b1 & 0xffff0000u);
    acc[12] += __uint_as_float(b2 << 16); acc[13] += __uint_as_float(b2 & 0xffff0000u);
    acc[14] += __uint_as_float(b3 << 16); acc[15] += __uint_as_float(b3 & 0xffff0000u);
  }

  const float dv = dinv[node];
  u16x8 pav, pbv;
#pragma unroll
  for (int q = 0; q < 8; ++q) {
    pav[q] = f2bf(fmaxf(acc[q] * dv + bias[kh * 8 + q], 0.0f));
    pbv[q] = f2bf(fmaxf(acc[8 + q] * dv + bias[32 + kh * 8 + q], 0.0f));
  }
  const bf16x8 pa = (bf16x8)pav, pb = (bf16x8)pbv;

  f32x4 gac[4];
  const f32x4 zz = {0.f, 0.f, 0.f, 0.f};
#pragma unroll
  for (int ct = 0; ct < 4; ++ct) gac[ct] = zz;
#pragma unroll
  for (int ct = 0; ct < 4; ++ct) {
    const int n = ct * 16 + lr;
    const int bb0 = (n * 128 + kh * 16) ^ ((n & 7) << 4);
    const int bb1 = (n * 128 + 64 + kh * 16) ^ ((n & 7) << 4);
    bf16x8 bh0 = *(const bf16x8*)&Wh[bb0 >> 1];
    bf16x8 bl0 = *(const bf16x8*)&Wl_[bb0 >> 1];
    bf16x8 bh1 = *(const bf16x8*)&Wh[bb1 >> 1];
    bf16x8 bl1 = *(const bf16x8*)&Wl_[bb1 >> 1];
    gac[ct] = __builtin_amdgcn_mfma_f32_16x16x32_bf16(pa, bl0, gac[ct], 0, 0, 0);
    gac[ct] = __builtin_amdgcn_mfma_f32_16x16x32_bf16(pa, bh0, gac[ct], 0, 0, 0);
    gac[ct] = __builtin_amdgcn_mfma_f32_16x16x32_bf16(pb, bl1, gac[ct], 0, 0, 0);
    gac[ct] = __builtin_amdgcn_mfma_f32_16x16x32_bf16(pb, bh1, gac[ct], 0, 0, 0);
  }

#pragma unroll
  for (int r = 0; r < 4; ++r) {
    int oslot = slot0 + kh * 4 + r;
    if (oslot < NN) {
      int onode = perm[NN - 1 - oslot];
      float odv = dinv[onode];
#pragma unroll
      for (int ct = 0; ct < 4; ++ct)
        Un[(size_t)onode * 64 + ct * 16 + lr] = f2bf(gac[ct][r] * odv);
    }
  }
}

// ---------------- fused conv1-agg + Wc1 GEMM: hc = dinv.*(relu(dinv*agg(Tb)+b1) @ Wc1) ----------------
// 8-edge per-kc phased gather (8 outstanding); full (n&15) swizzle on 256B W rows.

__global__ __launch_bounds__(256) void fcv_k(const uint4* __restrict__ U,
                                             const ushort_t* __restrict__ Fh, const ushort_t* __restrict__ Fl,
                                             const int* __restrict__ perm, const int* __restrict__ rowstart,
                                             const int* __restrict__ cnt, const int* __restrict__ csr,
                                             const float* __restrict__ dinv, const float* __restrict__ bias,
                                             ushort_t* __restrict__ hc) {
  __shared__ ushort_t Wh[64 * 128], Wl_[64 * 128];   // 32 KB
  const int t = threadIdx.x;
  for (int idx = t; idx < 64 * 16; idx += 256) {
    int n = idx >> 4, kq = idx & 15;
    u16x8 hv = *(const u16x8*)&Fh[(size_t)n * 192 + kq * 8];
    u16x8 lv = *(const u16x8*)&Fl[(size_t)n * 192 + kq * 8];
    int byt = (n * 256 + kq * 16) ^ ((n & 15) << 4);
    *(u16x8*)&Wh[byt >> 1] = hv;
    *(u16x8*)&Wl_[byt >> 1] = lv;
  }
  __syncthreads();

  const int w = t >> 6, l = t & 63;
  const int lr = l & 15, kh = l >> 4;
  const int slot0 = blockIdx.x * 64 + w * 16;
  const int slot = min(slot0 + lr, NN - 1);
  const int node = perm[NN - 1 - slot];

  // gather: acc[kc][0..7] = elems kc*32 + kh*8 .. +8
  float acc[4][8];
#pragma unroll
  for (int kc = 0; kc < 4; ++kc) {
    uint4 v = U[(size_t)node * 16 + kc * 4 + kh];
    uint_t u[4] = {v.x, v.y, v.z, v.w};
#pragma unroll
    for (int q = 0; q < 4; ++q) {
      acc[kc][2 * q]     = __uint_as_float(u[q] << 16);
      acc[kc][2 * q + 1] = __uint_as_float(u[q] & 0xffff0000u);
    }
  }
  int s = rowstart[node], c = cnt[node];
  int j = 0;
  for (; j + 8 <= c; j += 8) {
    int idx[8];
#pragma unroll
    for (int u = 0; u < 8; ++u) idx[u] = csr[s + j + u];
#pragma unroll
    for (int kc = 0; kc < 4; ++kc) {
      uint4 v[8];
#pragma unroll
      for (int u = 0; u < 8; ++u) v[u] = U[(size_t)idx[u] * 16 + kc * 4 + kh];
#pragma unroll
      for (int u = 0; u < 8; ++u) {
        uint_t q0 = v[u].x, q1 = v[u].y, q2 = v[u].z, q3 = v[u].w;
        acc[kc][0] += __uint_as_float(q0 << 16); acc[kc][1] += __uint_as_float(q0 & 0xffff0000u);
        acc[kc][2] += __uint_as_float(q1 << 16); acc[kc][3] += __uint_as_float(q1 & 0xffff0000u);
        acc[kc][4] += __uint_as_float(q2 << 16); acc[kc][5] += __uint_as_float(q2 & 0xffff0000u);
        acc[kc][6] += __uint_as_float(q3 << 16); acc[kc][7] += __uint_as_float(q3 & 0xffff0000u);
      }
    }
  }
  for (; j < c; ++j) {
    int sn = csr[s + j];
#pragma unroll
    for (int kc = 0; kc < 4; ++kc) {
      uint4 v = U[(size_t)sn * 16 + kc * 4 + kh];
      uint_t u[4] = {v.x, v.y, v.z, v.w};
#pragma unroll
      for (int q = 0; q < 4; ++q) {
        acc[kc][2 * q]     += __uint_as_float(u[q] << 16);
        acc[kc][2 * q + 1] += __uint_as_float(u[q] & 0xffff0000u);
      }
    }
  }

  // P = relu(dinv*acc + b1) -> bf16 frags (same rounding as before)
  const float dv = dinv[node];
  bf16x8 pa[4];
#pragma unroll
  for (int kc = 0; kc < 4; ++kc) {
    u16x8 pv;
#pragma unroll
    for (int q = 0; q < 8; ++q)
      pv[q] = f2bf(fmaxf(acc[kc][q] * dv + bias[kc * 32 + kh * 8 + q], 0.0f));
    pa[kc] = (bf16x8)pv;
  }

  // GEMM: V = P @ Wc1
  f32x4 gac[4];
  const f32x4 zz = {0.f, 0.f, 0.f, 0.f};
#pragma unroll
  for (int ct = 0; ct < 4; ++ct) gac[ct] = zz;
#pragma unroll
  for (int ct = 0; ct < 4; ++ct) {
    const int n = ct * 16 + lr;
#pragma unroll
    for (int kc = 0; kc < 4; ++kc) {
      const int bb = (n * 256 + kc * 64 + kh * 16) ^ ((n & 15) << 4);
      bf16x8 bh = *(const bf16x8*)&Wh[bb >> 1];
      bf16x8 bl = *(const bf16x8*)&Wl_[bb >> 1];
      gac[ct] = __builtin_amdgcn_mfma_f32_16x16x32_bf16(pa[kc], bl, gac[ct], 0, 0, 0);
      gac[ct] = __builtin_amdgcn_mfma_f32_16x16x32_bf16(pa[kc], bh, gac[ct], 0, 0, 0);
    }
  }

#pragma unroll
  for (int r = 0; r < 4; ++r) {
    int oslot = slot0 + kh * 4 + r;
    if (oslot < NN) {
      int onode = perm[NN - 1 - oslot];
      float odv = dinv[onode];
#pragma unroll
      for (int ct = 0; ct < 4; ++ct)
        hc[(size_t)onode * 64 + ct * 16 + lr] = f2bf(gac[ct][r] * odv);
    }
  }
}

// ---------------- fused tail: uB = hc + dinv.*(relu(dinv*agg(U8)+b8) @ Wc2) ----------------

__global__ __launch_bounds__(256) void ftail_k(const uint4* __restrict__ U,
                                               const ushort_t* __restrict__ Fh, const ushort_t* __restrict__ Fl,
                                               const int* __restrict__ perm, const int* __restrict__ rowstart,
                                               const int* __restrict__ cnt, const int* __restrict__ csr,
                                               const float* __restrict__ dinv, const float* __restrict__ bias,
                                               const ushort_t* __restrict__ hc, ushort_t* __restrict__ Un) {
  __shared__ ushort_t Wh[64 * 64], Wl_[64 * 64];
  const int t = threadIdx.x;
  for (int idx = t; idx < 64 * 8; idx += 256) {
    int n = idx >> 3, kq = idx & 7;
    u16x8 hv = *(const u16x8*)&Fh[(size_t)n * 192 + 128 + kq * 8];
    u16x8 lv = *(const u16x8*)&Fl[(size_t)n * 192 + 128 + kq * 8];
    int byt = (n * 128 + kq * 16) ^ ((n & 7) << 4);
    *(u16x8*)&Wh[byt >> 1] = hv;
    *(u16x8*)&Wl_[byt >> 1] = lv;
  }
  __syncthreads();

  const int w = t >> 6, l = t & 63;
  const int lr = l & 15, kh = l >> 4;
  const int slot0 = blockIdx.x * 64 + w * 16;
  const int slot = min(slot0 + lr, NN - 1);
  const int node = perm[NN - 1 - slot];

  float acc[16];
  {
    uint4 a = U[(size_t)node * 8 + kh];
    uint4 b = U[(size_t)node * 8 + 4 + kh];
    uint_t ua[4] = {a.x, a.y, a.z, a.w};
    uint_t ub[4] = {b.x, b.y, b.z, b.w};
#pragma unroll
    for (int q = 0; q < 4; ++q) {
      acc[2 * q]      = __uint_as_float(ua[q] << 16);
      acc[2 * q + 1]  = __uint_as_float(ua[q] & 0xffff0000u);
      acc[8 + 2 * q]     = __uint_as_float(ub[q] << 16);
      acc[8 + 2 * q + 1] = __uint_as_float(ub[q] & 0xffff0000u);
    }
  }
  int s = rowstart[node], c = cnt[node];
  int j = 0;
  for (; j + 8 <= c; j += 8) {
    int idx[8];
#pragma unroll
    for (int u = 0; u < 8; ++u) idx[u] = csr[s + j + u];
    uint4 v[8];
#pragma unroll
    for (int u = 0; u < 8; ++u) v[u] = U[(size_t)idx[u] * 8 + kh];
#pragma unroll
    for (int u = 0; u < 8; ++u) {
      uint_t a0 = v[u].x, a1 = v[u].y, a2 = v[u].z, a3 = v[u].w;
      acc[0] += __uint_as_float(a0 << 16); acc[1] += __uint_as_float(a0 & 0xffff0000u);
      acc[2] += __uint_as_float(a1 << 16); acc[3] += __uint_as_float(a1 & 0xffff0000u);
      acc[4] += __uint_as_float(a2 << 16); acc[5] += __uint_as_float(a2 & 0xffff0000u);
      acc[6] += __uint_as_float(a3 << 16); acc[7] += __uint_as_float(a3 & 0xffff0000u);
    }
#pragma unroll
    for (int u = 0; u < 8; ++u) v[u] = U[(size_t)idx[u] * 8 + 4 + kh];
#pragma unroll
    for (int u = 0; u < 8; ++u) {
      uint_t b0 = v[u].x, b1 = v[u].y, b2 = v[u].z, b3 = v[u].w;
      acc[8]  += __uint_as_float(b0 << 16); acc[9]  += __uint_as_float(b0 & 0xffff0000u);
      acc[10] += __uint_as_float(b1 << 16); acc[11] += __uint_as_float(b1 & 0xffff0000u);
      acc[12] += __uint_as_float(b2 << 16); acc[13] += __uint_as_float(b2 & 0xffff0000u);
      acc[14] += __uint_as_float(b3 << 16); acc[15] += __uint_as_float(b3 & 0xffff0000u);
    }
  }
  for (; j < c; ++j) {
    int sn = csr[s + j];
    uint4 a = U[(size_t)sn * 8 + kh];
    uint4 b = U[(size_t)sn * 8 + 4 + kh];
    uint_t a0 = a.x, a1 = a.y, a2 = a.z, a3 = a.w;
    uint_t b0 = b.x, b1 = b.y, b2 = b.z, b3 = b.w;
    acc[0] += __uint_as_float(a0 << 16); acc[1] += __uint_as_float(a0 & 0xffff0000u);
    acc[2] += __uint_as_float(a1 << 16); acc[3] += __uint_as_float(a1 & 0xffff0000u);
    acc[4] += __uint_as_float(a2 << 16); acc[5] += __uint_as_float(a2 & 0xffff0000u);
    acc[6] += __uint_as_float(a3 << 16); acc[7] += __uint_as_float(a3 & 0xffff0000u);
    acc[8]  += __uint_as_float(b0 << 16); acc[9]  += __uint_as_float(b0 & 0xffff0000u);
    acc[10] += __uint_as_float(b1 << 16); acc[11] += __uint_as_float(b1 & 0xffff0000u);
    acc[12] += __uint_as_float(b2 << 16); acc[13] += __uint_as_float(b2 & 0xffff0000u);
    acc[14] += __uint_as_float(b3 << 16); acc[15] += __uint_as_float(b3 & 0xffff0000u);
  }

  const float dv = dinv[node];
  u16x8 pav, pbv;
#pragma unroll
  for (int q = 0; q < 8; ++q) {
    pav[q] = f2bf(fmaxf(acc[q] * dv + bias[kh * 8 + q], 0.0f));
    pbv[q] = f2bf(fmaxf(acc[8 + q] * dv + bias[32 + kh * 8 + q], 0.0f));
  }
  const bf16x8 pa = (bf16x8)pav, pb = (bf16x8)pbv;

  f32x4 gac[4];
  const f32x4 zz = {0.f, 0.f, 0.f, 0.f};
#pragma unroll
  for (int ct = 0; ct < 4; ++ct) gac[ct] = zz;
#pragma unroll
  for (int ct = 0; ct < 4; ++ct) {
    const int n = ct * 16 + lr;
    const int bb0 = (n * 128 + kh * 16) ^ ((n & 7) << 4);
    const int bb1 = (n * 128 + 64 + kh * 16) ^ ((n & 7) << 4);
    bf16x8 bh0 = *(const bf16x8*)&Wh[bb0 >> 1];
    bf16x8 bl0 = *(const bf16x8*)&Wl_[bb0 >> 1];
    bf16x8 bh1 = *(const bf16x8*)&Wh[bb1 >> 1];
    bf16x8 bl1 = *(const bf16x8*)&Wl_[bb1 >> 1];
    gac[ct] = __builtin_amdgcn_mfma_f32_16x16x32_bf16(pa, bl0, gac[ct], 0, 0, 0);
    gac[ct] = __builtin_amdgcn_mfma_f32_16x16x32_bf16(pa, bh0, gac[ct], 0, 0, 0);
    gac[ct] = __builtin_amdgcn_mfma_f32_16x16x32_bf16(pb, bl1, gac[ct], 0, 0, 0);
    gac[ct] = __builtin_amdgcn_mfma_f32_16x16x32_bf16(pb, bh1, gac[ct], 0, 0, 0);
  }

#pragma unroll
  for (int r = 0; r < 4; ++r) {
    int oslot = slot0 + kh * 4 + r;
    if (oslot < NN) {
      int onode = perm[NN - 1 - oslot];
      float odv = dinv[onode];
#pragma unroll
      for (int ct = 0; ct < 4; ++ct) {
        int col = ct * 16 + lr;
        float v = gac[ct][r] * odv + bf2f(hc[(size_t)onode * 64 + col]);
        Un[(size_t)onode * 64 + col] = f2bf(v);
      }
    }
  }
}

// ---------------- aggregation (final only): out f32 = sigmoid(acc*dinv + bc) ----------------

template <int D, int MODE>
__global__ __launch_bounds__(256) void agg_k(const uint4* __restrict__ t, const int* __restrict__ perm,
                                             const int* __restrict__ rowstart, const int* __restrict__ cnt,
                                             const int* __restrict__ csr, const float* __restrict__ dinv,
                                             const float* __restrict__ bias, void* __restrict__ outv) {
  constexpr int LPN = D / 8;
  int slot = blockIdx.x * (256 / LPN) + threadIdx.x / LPN;
  int lane = threadIdx.x % LPN;
  if (slot >= NN) return;
  int node = perm[NN - 1 - slot];

  float acc[8];
  uint4 sv = t[(size_t)node * LPN + lane];
  {
    uint_t u[4] = {sv.x, sv.y, sv.z, sv.w};
#pragma unroll
    for (int q = 0; q < 4; ++q) {
      acc[2 * q]     = __uint_as_float(u[q] << 16);
      acc[2 * q + 1] = __uint_as_float(u[q] & 0xffff0000u);
    }
  }
  int s = rowstart[node], c = cnt[node];
  int j = 0;
  for (; j + 8 <= c; j += 8) {
    int idx[8];
#pragma unroll
    for (int u = 0; u < 8; ++u) idx[u] = csr[s + j + u];
    uint4 v[8];
#pragma unroll
    for (int u = 0; u < 8; ++u) v[u] = t[(size_t)idx[u] * LPN + lane];
#pragma unroll
    for (int u = 0; u < 8; ++u) {
      uint_t q0 = v[u].x, q1 = v[u].y, q2 = v[u].z, q3 = v[u].w;
      acc[0] += __uint_as_float(q0 << 16); acc[1] += __uint_as_float(q0 & 0xffff0000u);
      acc[2] += __uint_as_float(q1 << 16); acc[3] += __uint_as_float(q1 & 0xffff0000u);
      acc[4] += __uint_as_float(q2 << 16); acc[5] += __uint_as_float(q2 & 0xffff0000u);
      acc[6] += __uint_as_float(q3 << 16); acc[7] += __uint_as_float(q3 & 0xffff0000u);
    }
  }
  for (; j < c; ++j) {
    int sn = csr[s + j];
    uint4 v = t[(size_t)sn * LPN + lane];
    uint_t q0 = v.x, q1 = v.y, q2 = v.z, q3 = v.w;
    acc[0] += __uint_as_float(q0 << 16); acc[1] += __uint_as_float(q0 & 0xffff0000u);
    acc[2] += __uint_as_float(q1 << 16); acc[3] += __uint_as_float(q1 & 0xffff0000u);
    acc[4] += __uint_as_float(q2 << 16); acc[5] += __uint_as_float(q2 & 0xffff0000u);
    acc[6] += __uint_as_float(q3 << 16); acc[7] += __uint_as_float(q3 & 0xffff0000u);
  }
  float dv = dinv[node];
  if constexpr (MODE == 0) {
    u16x8 ov;
#pragma unroll
    for (int q = 0; q < 8; ++q) {
      float o = fmaxf(acc[q] * dv + bias[lane * 8 + q], 0.0f);
      ov[q] = f2bf(o);
    }
    *(u16x8*)&((ushort_t*)outv)[(size_t)node * D + lane * 8] = ov;
  } else {
    float o[8];
#pragma unroll
    for (int q = 0; q < 8; ++q) {
      float v2 = acc[q] * dv + bias[lane * 8 + q];
      o[q] = 1.0f / (1.0f + __expf(-v2));
    }
    float4 o0 = {o[0], o[1], o[2], o[3]};
    float4 o1 = {o[4], o[5], o[6], o[7]};
    float* outf = (float*)outv;
    *(float4*)&outf[(size_t)node * D + lane * 8] = o0;
    *(float4*)&outf[(size_t)node * D + lane * 8 + 4] = o1;
  }
}

// ---------------- launch ----------------

extern "C" void kernel_launch(void* const* d_in, const int* in_sizes, int n_in,
                              void* d_out, int out_size, void* d_ws, size_t ws_size,
                              hipStream_t stream) {
  const float* x  = (const float*)d_in[0];
  const float* y  = (const float*)d_in[1];
  const int* ei   = (const int*)d_in[2];
  const float* Wg1 = (const float*)d_in[3];
  const float* bg1 = (const float*)d_in[4];
  const float* Wg2 = (const float*)d_in[5];
  const float* bg2 = (const float*)d_in[6];   // folded into bc
  const float* Wl  = (const float*)d_in[7];
  const float* bl  = (const float*)d_in[8];
  const float* Wf  = (const float*)d_in[9];
  const float* bf  = (const float*)d_in[10];
  float* out = (float*)d_out;

  char* ws = (char*)d_ws;
  size_t off = 0;
  auto alloc = [&](size_t bytes) { void* p = ws + off; off += (bytes + 511) & ~(size_t)511; return p; };
  int* cnt      = (int*)alloc((size_t)NN * 4);
  int* rowstart = (int*)alloc((size_t)NN * 4);
  int* blocksum = (int*)alloc(512);
  float* dinv   = (float*)alloc((size_t)NN * 4);
  int* csr      = (int*)alloc((size_t)NE * 4);
  int* bcnt     = (int*)alloc((size_t)NB * 4);   // 3128 -> 3584
  int* dbin     = (int*)alloc(DBINS * 4);        // adjacent: one memset covers both (4096 B)
  uint_t* pairs = (uint_t*)alloc((size_t)NB * BCAP * 4);
  int* perm     = (int*)alloc((size_t)NN * 4);
  int* dcur     = (int*)alloc(DBINS * 4);
  ushort_t* Tb  = (ushort_t*)alloc((size_t)NN * 128 * 2);  // conv1 staging; halves = U ping/pong later
  ushort_t* Ub  = (ushort_t*)alloc((size_t)NN * 64 * 2);   // hc buffer
  ushort_t* G1h = (ushort_t*)alloc(128 * 128 * 2);
  ushort_t* G1l = (ushort_t*)alloc(128 * 128 * 2);
  ushort_t* Lh  = (ushort_t*)alloc(10 * 64 * 64 * 2);
  ushort_t* Ll  = (ushort_t*)alloc(10 * 64 * 64 * 2);
  ushort_t* Fh  = (ushort_t*)alloc(64 * 192 * 2);          // composed tail weight (k-major)
  ushort_t* Fl  = (ushort_t*)alloc(64 * 192 * 2);
  float* bc     = (float*)alloc(64 * 4);                   // composed tail bias
  ushort_t* uA = Tb;                     // U ping (Tb dead after fcv)
  ushort_t* uB = Tb + (size_t)NN * 64;   // U pong

  const int* esrc = ei;
  const int* edst = ei + NE;

  wcprep_k<<<272, 256, 0, stream>>>(Wg1, Wl, Wg2, Wf, bg2, bl + (size_t)9 * 64, bf,
                                    G1h, G1l, Lh, Ll, Fh, Fl, bc);
  hipMemsetAsync(bcnt, 0, 4096, stream);   // covers bcnt + dbin (adjacent allocs)
  bucketA_k<<<BKBLK, 512, 0, stream>>>(esrc, edst, bcnt, pairs);
  count2_k<<<NB, 256, 0, stream>>>(bcnt, pairs, cnt, dinv, dbin);
  scan1<<<98, 1024, 0, stream>>>(cnt, rowstart, blocksum);
  scan2<<<1, 1, 0, stream>>>(blocksum, 98, dbin, dcur);
  scan3<<<98, 1024, 0, stream>>>(rowstart, blocksum);
  fillplace_k<<<NB + (NN + 255) / 256, 256, 0, stream>>>(bcnt, pairs, rowstart, csr, cnt, dcur, perm);

  const int GG = (NN + 63) / 64;

  // feature conv1 GEMM, then fused conv1-agg + Wc1 projection -> hc
  mgemm_k<128, 128><<<GG, 256, 0, stream>>>(x, G1h, G1l, dinv, Tb);
  fcv_k<<<GG, 256, 0, stream>>>((const uint4*)Tb, Fh, Fl, perm, rowstart, cnt, csr,
                                dinv, bg1, Ub);

  // label chain: U0 = dinv.*(y W0); 8 fused layers; fused tail adds hc
  mgemmW_k<64, 0, 64, true><<<GG, 256, 0, stream>>>(y, nullptr, Lh, Ll, dinv, uA);
  const ushort_t* uin = uA;
  for (int j = 0; j < 8; ++j) {
    ushort_t* uout = (j & 1) ? uA : uB;
    flay_k<<<GG, 256, 0, stream>>>((const uint4*)uin, Lh + (size_t)(j + 1) * 4096, Ll + (size_t)(j + 1) * 4096,
                                   perm, rowstart, cnt, csr, dinv, bl + (size_t)j * 64, uout);
    uin = uout;
  }
  // uin = U8 (in uA); ftail: uB = hc + dinv.*(relu(dinv*agg(U8)+b8) @ Wc2)
  ftail_k<<<GG, 256, 0, stream>>>((const uint4*)uin, Fh, Fl, perm, rowstart, cnt, csr,
                                  dinv, bl + (size_t)8 * 64, Ub, uB);

  // final: out = sigmoid(S(uB) + bc)
  agg_k<64, 1><<<NN / 32, 256, 0, stream>>>((const uint4*)uB, perm, rowstart, cnt, csr, dinv, bc, out);
}

// Round 14
// 610.445 us; speedup vs baseline: 1.1556x; 1.1556x over previous
//
#include <hip/hip_runtime.h>
#include <math.h>

#define NN 100000
#define NE 1600000
#define NB 782      // dst buckets of 128 nodes
#define BCAP 3072   // bucket capacity (mean ~2046, 22 sigma safe)
#define BKBLK 128   // blocks in bucket build
#define BKCHUNK (NE / BKBLK)  // 12500 edges per block
#define DBINS 64    // degree bins for counting sort

typedef unsigned short ushort_t;
typedef unsigned int uint_t;
typedef __attribute__((ext_vector_type(8))) short bf16x8;
typedef __attribute__((ext_vector_type(8))) unsigned short u16x8;
typedef __attribute__((ext_vector_type(4))) float f32x4;

__device__ __forceinline__ ushort_t f2bf(float f) {
  uint_t u = __float_as_uint(f);
  u = (u + 0x7fffu + ((u >> 16) & 1u)) >> 16;   // round-to-nearest-even
  return (ushort_t)u;
}
__device__ __forceinline__ float bf2f(ushort_t h) {
  return __uint_as_float((uint_t)h << 16);
}

// ---------------- setup: bucketed CSR build (histogram + reserve + write) ----------------

__global__ __launch_bounds__(512) void bucketA_k(const int* __restrict__ src, const int* __restrict__ dst,
                                                 int* __restrict__ bcnt, uint_t* __restrict__ pairs) {
  __shared__ int h[NB];
  const int t = threadIdx.x;
  const int e0 = blockIdx.x * BKCHUNK;
  for (int b = t; b < NB; b += 512) h[b] = 0;
  __syncthreads();
  for (int i = t; i < BKCHUNK; i += 512) atomicAdd(&h[dst[e0 + i] >> 7], 1);
  __syncthreads();
  for (int b = t; b < NB; b += 512) h[b] = atomicAdd(&bcnt[b], h[b]);
  __syncthreads();
  for (int i = t; i < BKCHUNK; i += 512) {
    int s = src[e0 + i], d = dst[e0 + i];
    int b = d >> 7;
    int pos = atomicAdd(&h[b], 1);
    if (pos < BCAP) pairs[b * BCAP + pos] = ((uint_t)s << 7) | (uint_t)(d & 127);
  }
}

// count + dinv + degree-histogram fused
__global__ __launch_bounds__(256) void count2_k(const int* __restrict__ bcnt, const uint_t* __restrict__ pairs,
                                                int* __restrict__ cnt, float* __restrict__ dinv,
                                                int* __restrict__ dbin) {
  __shared__ int c[128];
  __shared__ int hb[DBINS];
  int b = blockIdx.x, t = threadIdx.x;
  if (t < 128) c[t] = 0;
  if (t >= 128 && t < 128 + DBINS) hb[t - 128] = 0;
  __syncthreads();
  int n = min(bcnt[b], BCAP);
  for (int i = t; i < n; i += 256) atomicAdd(&c[pairs[b * BCAP + i] & 127], 1);
  __syncthreads();
  if (t < 128) {
    int node = b * 128 + t;
    if (node < NN) {
      int cc = c[t];
      cnt[node] = cc;
      dinv[node] = rsqrtf((float)(cc + 1));
      atomicAdd(&hb[min(cc, DBINS - 1)], 1);
    }
  }
  __syncthreads();
  if (t < DBINS && hb[t]) atomicAdd(&dbin[t], hb[t]);
}

__global__ __launch_bounds__(1024) void scan1(const int* __restrict__ cnt, int* __restrict__ rowstart,
                                              int* __restrict__ blocksum) {
  __shared__ int s[1024];
  int t = threadIdx.x;
  int i = blockIdx.x * 1024 + t;
  int v = (i < NN) ? cnt[i] : 0;
  s[t] = v;
  __syncthreads();
  for (int off = 1; off < 1024; off <<= 1) {
    int add = (t >= off) ? s[t - off] : 0;
    __syncthreads();
    s[t] += add;
    __syncthreads();
  }
  if (i < NN) rowstart[i] = s[t] - v;   // exclusive
  if (t == 1023) blocksum[blockIdx.x] = s[1023];
}

// blocksum scan + degree-bin scan fused
__global__ void scan2(int* blocksum, int nb, const int* __restrict__ dbin, int* __restrict__ dcur) {
  if (threadIdx.x == 0 && blockIdx.x == 0) {
    int acc = 0;
    for (int b = 0; b < nb; ++b) { int v = blocksum[b]; blocksum[b] = acc; acc += v; }
    int a2 = 0;
    for (int b = 0; b < DBINS; ++b) { dcur[b] = a2; a2 += dbin[b]; }
  }
}

__global__ __launch_bounds__(1024) void scan3(int* __restrict__ rowstart, const int* __restrict__ blocksum) {
  int i = blockIdx.x * 1024 + threadIdx.x;
  if (i < NN) rowstart[i] += blocksum[blockIdx.x];
}

// CSR fill (blocks 0..NB-1) + degree-sort placement (blocks NB..) fused
__global__ __launch_bounds__(256) void fillplace_k(const int* __restrict__ bcnt, const uint_t* __restrict__ pairs,
                                                   const int* __restrict__ rowstart, int* __restrict__ csr,
                                                   const int* __restrict__ cnt, int* __restrict__ dcur,
                                                   int* __restrict__ perm) {
  int t = threadIdx.x;
  if (blockIdx.x < NB) {
    __shared__ int cur[128];
    int b = blockIdx.x;
    if (t < 128) cur[t] = 0;
    __syncthreads();
    int n = min(bcnt[b], BCAP);
    for (int i = t; i < n; i += 256) {
      uint_t p = pairs[b * BCAP + i];
      int lo = p & 127;
      int pos = rowstart[b * 128 + lo] + atomicAdd(&cur[lo], 1);
      csr[pos] = (int)(p >> 7);
    }
  } else {
    __shared__ int h[DBINS];
    __shared__ int lbase[DBINS];
    int i = (blockIdx.x - NB) * 256 + t;
    if (t < DBINS) h[t] = 0;
    __syncthreads();
    int bin = 0, lrank = 0;
    if (i < NN) { bin = min(cnt[i], DBINS - 1); lrank = atomicAdd(&h[bin], 1); }
    __syncthreads();
    if (t < DBINS) lbase[t] = h[t] ? atomicAdd(&dcur[t], h[t]) : 0;
    __syncthreads();
    if (i < NN) perm[lbase[bin] + lrank] = i;
  }
}

// ---------------- weight prep (transpose + split) and tail composition, fused ----------------

__global__ __launch_bounds__(256) void wcprep_k(const float* __restrict__ Wg1, const float* __restrict__ Wl,
                                                const float* __restrict__ W2, const float* __restrict__ Wf,
                                                const float* __restrict__ b2, const float* __restrict__ b9,
                                                const float* __restrict__ bfb,
                                                ushort_t* __restrict__ G1h, ushort_t* __restrict__ G1l,
                                                ushort_t* __restrict__ Lh, ushort_t* __restrict__ Ll,
                                                ushort_t* __restrict__ Fh, ushort_t* __restrict__ Fl,
                                                float* __restrict__ bc) {
  if (blockIdx.x < 224) {   // wprep: Wg1 + Wl
    int i = blockIdx.x * 256 + threadIdx.x;   // 0..57343
    if (i >= 57344) return;
    float w;
    ushort_t *ph, *pl;
    size_t di;
    if (i < 16384) {           // Wg1 128x128
      int k = i >> 7, n = i & 127;
      w = Wg1[i]; di = (size_t)n * 128 + k; ph = G1h; pl = G1l;
    } else {                   // Wl 10 x 64x64
      int i2 = i - 16384;
      int j = i2 >> 12, r = i2 & 4095;
      int k = r >> 6, n = r & 63;
      w = Wl[i2]; di = (size_t)j * 4096 + n * 64 + k; ph = Lh; pl = Ll;
    }
    ushort_t h = f2bf(w);
    ph[di] = h;
    pl[di] = f2bf(w - bf2f(h));
  } else {                  // ccomp: Wc = [W2*Wf1 ; W9*Wf2], bc
    const float* W9 = Wl + (size_t)9 * 4096;
    int i = (blockIdx.x - 224) * 256 + threadIdx.x;   // 0..12287
    if (i >= 12288) return;
    int k = i >> 6, n = i & 63;
    float acc = 0.0f;
    if (k < 128) {
      for (int j = 0; j < 128; ++j) acc += W2[k * 128 + j] * Wf[j * 64 + n];
    } else {
      int k2 = k - 128;
      for (int j = 0; j < 64; ++j) acc += W9[k2 * 64 + j] * Wf[(128 + j) * 64 + n];
    }
    ushort_t h = f2bf(acc);
    Fh[(size_t)n * 192 + k] = h;
    Fl[(size_t)n * 192 + k] = f2bf(acc - bf2f(h));
    if (k == 0) {
      float b = bfb[n];
      for (int j = 0; j < 128; ++j) b += b2[j] * Wf[j * 64 + n];
      for (int j = 0; j < 64; ++j) b += b9[j] * Wf[(128 + j) * 64 + n];
      bc[n] = b;
    }
  }
}

// ---------------- conv1 MFMA GEMM (K=128, chunked LDS staging, bf16x3, proven) ----------------

template <int K, int DC>
__global__ __launch_bounds__(256) void mgemm_k(const float* __restrict__ A,
                                               const ushort_t* __restrict__ Wth, const ushort_t* __restrict__ Wtl,
                                               const float* __restrict__ dinv, ushort_t* __restrict__ C) {
  constexpr int NCH = K / 64;
  __shared__ ushort_t Ah[64 * 64], Al[64 * 64];
  __shared__ ushort_t Wh[DC * 64], Wl_[DC * 64];
  const int t = threadIdx.x;
  const int row0 = blockIdx.x * 64;
  const int w = t >> 6, l = t & 63;
  const int lr = l & 15, kh = l >> 4;

  f32x4 acc[DC / 16];
  const f32x4 zz = {0.f, 0.f, 0.f, 0.f};
#pragma unroll
  for (int ct = 0; ct < DC / 16; ++ct) acc[ct] = zz;

  for (int kc = 0; kc < NCH; ++kc) {
    if (kc) __syncthreads();
#pragma unroll
    for (int it = 0; it < 4; ++it) {
      int idx = t + it * 256;
      int row = idx >> 4, kq = idx & 15;
      int gr = min(row0 + row, NN - 1);
      float4 a = *(const float4*)&A[(size_t)gr * K + kc * 64 + kq * 4];
      ushort4 h, lo;
      h.x = f2bf(a.x); lo.x = f2bf(a.x - bf2f(h.x));
      h.y = f2bf(a.y); lo.y = f2bf(a.y - bf2f(h.y));
      h.z = f2bf(a.z); lo.z = f2bf(a.z - bf2f(h.z));
      h.w = f2bf(a.w); lo.w = f2bf(a.w - bf2f(h.w));
      int byt = (row * 128 + kq * 8) ^ ((row & 7) << 4);
      *(ushort4*)&Ah[byt >> 1] = h;
      *(ushort4*)&Al[byt >> 1] = lo;
    }
    for (int idx = t; idx < DC * 8; idx += 256) {
      int n = idx >> 3, kq = idx & 7;
      u16x8 hv = *(const u16x8*)&Wth[(size_t)n * K + kc * 64 + kq * 8];
      u16x8 lv = *(const u16x8*)&Wtl[(size_t)n * K + kc * 64 + kq * 8];
      int byt = (n * 128 + kq * 16) ^ ((n & 7) << 4);
      *(u16x8*)&Wh[byt >> 1] = hv;
      *(u16x8*)&Wl_[byt >> 1] = lv;
    }
    __syncthreads();
#pragma unroll
    for (int kc2 = 0; kc2 < 2; ++kc2) {
      int arow = w * 16 + lr;
      int ab = (arow * 128 + kc2 * 64 + kh * 16) ^ ((arow & 7) << 4);
      bf16x8 ah = *(const bf16x8*)&Ah[ab >> 1];
      bf16x8 al = *(const bf16x8*)&Al[ab >> 1];
#pragma unroll
      for (int ct = 0; ct < DC / 16; ++ct) {
        int n = ct * 16 + lr;
        int bb = (n * 128 + kc2 * 64 + kh * 16) ^ ((n & 7) << 4);
        bf16x8 bh = *(const bf16x8*)&Wh[bb >> 1];
        bf16x8 bl = *(const bf16x8*)&Wl_[bb >> 1];
        acc[ct] = __builtin_amdgcn_mfma_f32_16x16x32_bf16(al, bh, acc[ct], 0, 0, 0);
        acc[ct] = __builtin_amdgcn_mfma_f32_16x16x32_bf16(ah, bl, acc[ct], 0, 0, 0);
        acc[ct] = __builtin_amdgcn_mfma_f32_16x16x32_bf16(ah, bh, acc[ct], 0, 0, 0);
      }
    }
  }
  float dv[4];
#pragma unroll
  for (int r = 0; r < 4; ++r) {
    int grow = row0 + w * 16 + kh * 4 + r;
    dv[r] = (grow < NN) ? dinv[grow] : 0.0f;
  }
#pragma unroll
  for (int ct = 0; ct < DC / 16; ++ct) {
    int col = ct * 16 + lr;
#pragma unroll
    for (int r = 0; r < 4; ++r) {
      int grow = row0 + w * 16 + kh * 4 + r;
      if (grow < NN) C[(size_t)grow * DC + col] = f2bf(acc[ct][r] * dv[r]);
    }
  }
}

// ---------------- W-resident MFMA GEMM (label-chain start): W in LDS once, A global->reg ----------------

template <int K1, int K2, int DC, bool AF32>
__global__ __launch_bounds__(256) void mgemmW_k(const void* __restrict__ A1v, const void* __restrict__ A2v,
                                                const ushort_t* __restrict__ Wth, const ushort_t* __restrict__ Wtl,
                                                const float* __restrict__ dinv, ushort_t* __restrict__ C) {
  constexpr int K = K1 + K2;
  __shared__ ushort_t Wh[DC * K], Wl_[DC * K];
  const int t = threadIdx.x;
  const int w = t >> 6, l = t & 63;
  const int lr = l & 15, kh = l >> 4;
  const int row0 = blockIdx.x * 64;
  const int arow = min(row0 + w * 16 + lr, NN - 1);

  for (int idx = t; idx < DC * (K / 8); idx += 256) {
    int n = idx / (K / 8), kq = idx % (K / 8);
    u16x8 hv = *(const u16x8*)&Wth[(size_t)n * K + kq * 8];
    u16x8 lv = *(const u16x8*)&Wtl[(size_t)n * K + kq * 8];
    int byt = (n * K * 2 + kq * 16) ^ ((n & 7) << 4);
    *(u16x8*)&Wh[byt >> 1] = hv;
    *(u16x8*)&Wl_[byt >> 1] = lv;
  }
  __syncthreads();

  f32x4 acc[DC / 16];
  const f32x4 zz = {0.f, 0.f, 0.f, 0.f};
#pragma unroll
  for (int ct = 0; ct < DC / 16; ++ct) acc[ct] = zz;

#pragma unroll
  for (int kc = 0; kc < K / 32; ++kc) {
    const int kbase = kc * 32 + kh * 8;
    bf16x8 ah, al;
    if constexpr (AF32) {
      const float* Ap;
      if (K2 > 0 && kbase >= K1) Ap = &((const float*)A2v)[(size_t)arow * K2 + kbase - K1];
      else                       Ap = &((const float*)A1v)[(size_t)arow * K1 + kbase];
      float4 a0 = *(const float4*)Ap;
      float4 a1 = *(const float4*)(Ap + 4);
      float av[8] = {a0.x, a0.y, a0.z, a0.w, a1.x, a1.y, a1.z, a1.w};
      u16x8 hv, lv;
#pragma unroll
      for (int e = 0; e < 8; ++e) {
        ushort_t h = f2bf(av[e]);
        hv[e] = h;
        lv[e] = f2bf(av[e] - bf2f(h));
      }
      ah = (bf16x8)hv; al = (bf16x8)lv;
    } else {
      const ushort_t* Ap;
      if (K2 > 0 && kbase >= K1) Ap = &((const ushort_t*)A2v)[(size_t)arow * K2 + kbase - K1];
      else                       Ap = &((const ushort_t*)A1v)[(size_t)arow * K1 + kbase];
      ah = *(const bf16x8*)Ap;
    }
#pragma unroll
    for (int ct = 0; ct < DC / 16; ++ct) {
      const int n = ct * 16 + lr;
      const int bb = (n * K * 2 + kc * 64 + kh * 16) ^ ((n & 7) << 4);
      bf16x8 bh = *(const bf16x8*)&Wh[bb >> 1];
      bf16x8 bl = *(const bf16x8*)&Wl_[bb >> 1];
      if constexpr (AF32) acc[ct] = __builtin_amdgcn_mfma_f32_16x16x32_bf16(al, bh, acc[ct], 0, 0, 0);
      acc[ct] = __builtin_amdgcn_mfma_f32_16x16x32_bf16(ah, bl, acc[ct], 0, 0, 0);
      acc[ct] = __builtin_amdgcn_mfma_f32_16x16x32_bf16(ah, bh, acc[ct], 0, 0, 0);
    }
  }

  float dv[4];
#pragma unroll
  for (int r = 0; r < 4; ++r) {
    int grow = row0 + w * 16 + kh * 4 + r;
    dv[r] = (grow < NN) ? dinv[grow] : 0.0f;
  }
#pragma unroll
  for (int ct = 0; ct < DC / 16; ++ct) {
    int col = ct * 16 + lr;
#pragma unroll
    for (int r = 0; r < 4; ++r) {
      int grow = row0 + w * 16 + kh * 4 + r;
      if (grow < NN) C[(size_t)grow * DC + col] = f2bf(acc[ct][r] * dv[r]);
    }
  }
}

// ---------------- fused label layer: agg_j (gather) + GEMM_{j+1} (W-resident, P in regs) ----------------

__global__ __launch_bounds__(256) void flay_k(const uint4* __restrict__ U,
                                              const ushort_t* __restrict__ Wth, const ushort_t* __restrict__ Wtl,
                                              const int* __restrict__ perm, const int* __restrict__ rowstart,
                                              const int* __restrict__ cnt, const int* __restrict__ csr,
                                              const float* __restrict__ dinv, const float* __restrict__ bias,
                                              ushort_t* __restrict__ Un) {
  __shared__ ushort_t Wh[64 * 64], Wl_[64 * 64];   // 16 KB
  const int t = threadIdx.x;
  for (int idx = t; idx < 64 * 8; idx += 256) {
    int n = idx >> 3, kq = idx & 7;
    u16x8 hv = *(const u16x8*)&Wth[(size_t)n * 64 + kq * 8];
    u16x8 lv = *(const u16x8*)&Wtl[(size_t)n * 64 + kq * 8];
    int byt = (n * 128 + kq * 16) ^ ((n & 7) << 4);
    *(u16x8*)&Wh[byt >> 1] = hv;
    *(u16x8*)&Wl_[byt >> 1] = lv;
  }
  __syncthreads();

  const int w = t >> 6, l = t & 63;
  const int lr = l & 15, kh = l >> 4;
  const int slot0 = blockIdx.x * 64 + w * 16;
  const int slot = min(slot0 + lr, NN - 1);
  const int node = perm[NN - 1 - slot];

  float acc[16];
  {
    uint4 a = U[(size_t)node * 8 + kh];
    uint4 b = U[(size_t)node * 8 + 4 + kh];
    uint_t ua[4] = {a.x, a.y, a.z, a.w};
    uint_t ub[4] = {b.x, b.y, b.z, b.w};
#pragma unroll
    for (int q = 0; q < 4; ++q) {
      acc[2 * q]      = __uint_as_float(ua[q] << 16);
      acc[2 * q + 1]  = __uint_as_float(ua[q] & 0xffff0000u);
      acc[8 + 2 * q]     = __uint_as_float(ub[q] << 16);
      acc[8 + 2 * q + 1] = __uint_as_float(ub[q] & 0xffff0000u);
    }
  }
  int s = rowstart[node], c = cnt[node];
  int j = 0;
  for (; j + 4 <= c; j += 4) {
    int idx[4];
#pragma unroll
    for (int u = 0; u < 4; ++u) idx[u] = csr[s + j + u];
    uint4 va[4], vb[4];
#pragma unroll
    for (int u = 0; u < 4; ++u) {
      va[u] = U[(size_t)idx[u] * 8 + kh];
      vb[u] = U[(size_t)idx[u] * 8 + 4 + kh];
    }
#pragma unroll
    for (int u = 0; u < 4; ++u) {
      uint_t a0 = va[u].x, a1 = va[u].y, a2 = va[u].z, a3 = va[u].w;
      uint_t b0 = vb[u].x, b1 = vb[u].y, b2 = vb[u].z, b3 = vb[u].w;
      acc[0] += __uint_as_float(a0 << 16); acc[1] += __uint_as_float(a0 & 0xffff0000u);
      acc[2] += __uint_as_float(a1 << 16); acc[3] += __uint_as_float(a1 & 0xffff0000u);
      acc[4] += __uint_as_float(a2 << 16); acc[5] += __uint_as_float(a2 & 0xffff0000u);
      acc[6] += __uint_as_float(a3 << 16); acc[7] += __uint_as_float(a3 & 0xffff0000u);
      acc[8]  += __uint_as_float(b0 << 16); acc[9]  += __uint_as_float(b0 & 0xffff0000u);
      acc[10] += __uint_as_float(b1 << 16); acc[11] += __uint_as_float(b1 & 0xffff0000u);
      acc[12] += __uint_as_float(b2 << 16); acc[13] += __uint_as_float(b2 & 0xffff0000u);
      acc[14] += __uint_as_float(b3 << 16); acc[15] += __uint_as_float(b3 & 0xffff0000u);
    }
  }
  for (; j < c; ++j) {
    int sn = csr[s + j];
    uint4 a = U[(size_t)sn * 8 + kh];
    uint4 b = U[(size_t)sn * 8 + 4 + kh];
    uint_t a0 = a.x, a1 = a.y, a2 = a.z, a3 = a.w;
    uint_t b0 = b.x, b1 = b.y, b2 = b.z, b3 = b.w;
    acc[0] += __uint_as_float(a0 << 16); acc[1] += __uint_as_float(a0 & 0xffff0000u);
    acc[2] += __uint_as_float(a1 << 16); acc[3] += __uint_as_float(a1 & 0xffff0000u);
    acc[4] += __uint_as_float(a2 << 16); acc[5] += __uint_as_float(a2 & 0xffff0000u);
    acc[6] += __uint_as_float(a3 << 16); acc[7] += __uint_as_float(a3 & 0xffff0000u);
    acc[8]  += __uint_as_float(b0 << 16); acc[9]  += __uint_as_float(b0 & 0xffff0000u);
    acc[10] += __uint_as_float(b1 << 16); acc[11] += __uint_as_float(b1 & 0xffff0000u);
    acc[12] += __uint_as_float(b2 << 16); acc[13] += __uint_as_float(b2 & 0xffff0000u);
    acc[14] += __uint_as_float(b3 << 16); acc[15] += __uint_as_float(b3 & 0xffff0000u);
  }

  const float dv = dinv[node];
  u16x8 pav, pbv;
#pragma unroll
  for (int q = 0; q < 8; ++q) {
    pav[q] = f2bf(fmaxf(acc[q] * dv + bias[kh * 8 + q], 0.0f));
    pbv[q] = f2bf(fmaxf(acc[8 + q] * dv + bias[32 + kh * 8 + q], 0.0f));
  }
  const bf16x8 pa = (bf16x8)pav, pb = (bf16x8)pbv;

  f32x4 gac[4];
  const f32x4 zz = {0.f, 0.f, 0.f, 0.f};
#pragma unroll
  for (int ct = 0; ct < 4; ++ct) gac[ct] = zz;
#pragma unroll
  for (int ct = 0; ct < 4; ++ct) {
    const int n = ct * 16 + lr;
    const int bb0 = (n * 128 + kh * 16) ^ ((n & 7) << 4);
    const int bb1 = (n * 128 + 64 + kh * 16) ^ ((n & 7) << 4);
    bf16x8 bh0 = *(const bf16x8*)&Wh[bb0 >> 1];
    bf16x8 bl0 = *(const bf16x8*)&Wl_[bb0 >> 1];
    bf16x8 bh1 = *(const bf16x8*)&Wh[bb1 >> 1];
    bf16x8 bl1 = *(const bf16x8*)&Wl_[bb1 >> 1];
    gac[ct] = __builtin_amdgcn_mfma_f32_16x16x32_bf16(pa, bl0, gac[ct], 0, 0, 0);
    gac[ct] = __builtin_amdgcn_mfma_f32_16x16x32_bf16(pa, bh0, gac[ct], 0, 0, 0);
    gac[ct] = __builtin_amdgcn_mfma_f32_16x16x32_bf16(pb, bl1, gac[ct], 0, 0, 0);
    gac[ct] = __builtin_amdgcn_mfma_f32_16x16x32_bf16(pb, bh1, gac[ct], 0, 0, 0);
  }

#pragma unroll
  for (int r = 0; r < 4; ++r) {
    int oslot = slot0 + kh * 4 + r;
    if (oslot < NN) {
      int onode = perm[NN - 1 - oslot];
      float odv = dinv[onode];
#pragma unroll
      for (int ct = 0; ct < 4; ++ct)
        Un[(size_t)onode * 64 + ct * 16 + lr] = f2bf(gac[ct][r] * odv);
    }
  }
}

// ---------------- fused conv1-agg + Wc1 GEMM: hc = dinv.*(relu(dinv*agg(Tb)+b1) @ Wc1) ----------------
// Round-12 gather (2-edge, full-row interleave); full (n&15) swizzle on 256B W rows (16 slots).

__global__ __launch_bounds__(256) void fcv_k(const uint4* __restrict__ U,
                                             const ushort_t* __restrict__ Fh, const ushort_t* __restrict__ Fl,
                                             const int* __restrict__ perm, const int* __restrict__ rowstart,
                                             const int* __restrict__ cnt, const int* __restrict__ csr,
                                             const float* __restrict__ dinv, const float* __restrict__ bias,
                                             ushort_t* __restrict__ hc) {
  __shared__ ushort_t Wh[64 * 128], Wl_[64 * 128];   // 32 KB
  const int t = threadIdx.x;
  for (int idx = t; idx < 64 * 16; idx += 256) {
    int n = idx >> 4, kq = idx & 15;
    u16x8 hv = *(const u16x8*)&Fh[(size_t)n * 192 + kq * 8];
    u16x8 lv = *(const u16x8*)&Fl[(size_t)n * 192 + kq * 8];
    int byt = (n * 256 + kq * 16) ^ ((n & 15) << 4);
    *(u16x8*)&Wh[byt >> 1] = hv;
    *(u16x8*)&Wl_[byt >> 1] = lv;
  }
  __syncthreads();

  const int w = t >> 6, l = t & 63;
  const int lr = l & 15, kh = l >> 4;
  const int slot0 = blockIdx.x * 64 + w * 16;
  const int slot = min(slot0 + lr, NN - 1);
  const int node = perm[NN - 1 - slot];

  // gather: acc[kc][0..7] = elems kc*32 + kh*8 .. +8
  float acc[4][8];
#pragma unroll
  for (int kc = 0; kc < 4; ++kc) {
    uint4 v = U[(size_t)node * 16 + kc * 4 + kh];
    uint_t u[4] = {v.x, v.y, v.z, v.w};
#pragma unroll
    for (int q = 0; q < 4; ++q) {
      acc[kc][2 * q]     = __uint_as_float(u[q] << 16);
      acc[kc][2 * q + 1] = __uint_as_float(u[q] & 0xffff0000u);
    }
  }
  int s = rowstart[node], c = cnt[node];
  int j = 0;
  for (; j + 2 <= c; j += 2) {
    int i0 = csr[s + j], i1 = csr[s + j + 1];
    uint4 v0[4], v1[4];
#pragma unroll
    for (int kc = 0; kc < 4; ++kc) {
      v0[kc] = U[(size_t)i0 * 16 + kc * 4 + kh];
      v1[kc] = U[(size_t)i1 * 16 + kc * 4 + kh];
    }
#pragma unroll
    for (int kc = 0; kc < 4; ++kc) {
      uint_t u0[4] = {v0[kc].x, v0[kc].y, v0[kc].z, v0[kc].w};
      uint_t u1[4] = {v1[kc].x, v1[kc].y, v1[kc].z, v1[kc].w};
#pragma unroll
      for (int q = 0; q < 4; ++q) {
        acc[kc][2 * q]     += __uint_as_float(u0[q] << 16) + __uint_as_float(u1[q] << 16);
        acc[kc][2 * q + 1] += __uint_as_float(u0[q] & 0xffff0000u) + __uint_as_float(u1[q] & 0xffff0000u);
      }
    }
  }
  for (; j < c; ++j) {
    int sn = csr[s + j];
#pragma unroll
    for (int kc = 0; kc < 4; ++kc) {
      uint4 v = U[(size_t)sn * 16 + kc * 4 + kh];
      uint_t u[4] = {v.x, v.y, v.z, v.w};
#pragma unroll
      for (int q = 0; q < 4; ++q) {
        acc[kc][2 * q]     += __uint_as_float(u[q] << 16);
        acc[kc][2 * q + 1] += __uint_as_float(u[q] & 0xffff0000u);
      }
    }
  }

  // P = relu(dinv*acc + b1) -> bf16 frags (same rounding as old H path)
  const float dv = dinv[node];
  bf16x8 pa[4];
#pragma unroll
  for (int kc = 0; kc < 4; ++kc) {
    u16x8 pv;
#pragma unroll
    for (int q = 0; q < 8; ++q)
      pv[q] = f2bf(fmaxf(acc[kc][q] * dv + bias[kc * 32 + kh * 8 + q], 0.0f));
    pa[kc] = (bf16x8)pv;
  }

  // GEMM: V = P @ Wc1
  f32x4 gac[4];
  const f32x4 zz = {0.f, 0.f, 0.f, 0.f};
#pragma unroll
  for (int ct = 0; ct < 4; ++ct) gac[ct] = zz;
#pragma unroll
  for (int ct = 0; ct < 4; ++ct) {
    const int n = ct * 16 + lr;
#pragma unroll
    for (int kc = 0; kc < 4; ++kc) {
      const int bb = (n * 256 + kc * 64 + kh * 16) ^ ((n & 15) << 4);
      bf16x8 bh = *(const bf16x8*)&Wh[bb >> 1];
      bf16x8 bl = *(const bf16x8*)&Wl_[bb >> 1];
      gac[ct] = __builtin_amdgcn_mfma_f32_16x16x32_bf16(pa[kc], bl, gac[ct], 0, 0, 0);
      gac[ct] = __builtin_amdgcn_mfma_f32_16x16x32_bf16(pa[kc], bh, gac[ct], 0, 0, 0);
    }
  }

#pragma unroll
  for (int r = 0; r < 4; ++r) {
    int oslot = slot0 + kh * 4 + r;
    if (oslot < NN) {
      int onode = perm[NN - 1 - oslot];
      float odv = dinv[onode];
#pragma unroll
      for (int ct = 0; ct < 4; ++ct)
        hc[(size_t)onode * 64 + ct * 16 + lr] = f2bf(gac[ct][r] * odv);
    }
  }
}

// ---------------- fused tail: uB = hc + dinv.*(relu(dinv*agg(U8)+b8) @ Wc2) ----------------

__global__ __launch_bounds__(256) void ftail_k(const uint4* __restrict__ U,
                                               const ushort_t* __restrict__ Fh, const ushort_t* __restrict__ Fl,
                                               const int* __restrict__ perm, const int* __restrict__ rowstart,
                                               const int* __restrict__ cnt, const int* __restrict__ csr,
                                               const float* __restrict__ dinv, const float* __restrict__ bias,
                                               const ushort_t* __restrict__ hc, ushort_t* __restrict__ Un) {
  __shared__ ushort_t Wh[64 * 64], Wl_[64 * 64];
  const int t = threadIdx.x;
  for (int idx = t; idx < 64 * 8; idx += 256) {
    int n = idx >> 3, kq = idx & 7;
    u16x8 hv = *(const u16x8*)&Fh[(size_t)n * 192 + 128 + kq * 8];
    u16x8 lv = *(const u16x8*)&Fl[(size_t)n * 192 + 128 + kq * 8];
    int byt = (n * 128 + kq * 16) ^ ((n & 7) << 4);
    *(u16x8*)&Wh[byt >> 1] = hv;
    *(u16x8*)&Wl_[byt >> 1] = lv;
  }
  __syncthreads();

  const int w = t >> 6, l = t & 63;
  const int lr = l & 15, kh = l >> 4;
  const int slot0 = blockIdx.x * 64 + w * 16;
  const int slot = min(slot0 + lr, NN - 1);
  const int node = perm[NN - 1 - slot];

  float acc[16];
  {
    uint4 a = U[(size_t)node * 8 + kh];
    uint4 b = U[(size_t)node * 8 + 4 + kh];
    uint_t ua[4] = {a.x, a.y, a.z, a.w};
    uint_t ub[4] = {b.x, b.y, b.z, b.w};
#pragma unroll
    for (int q = 0; q < 4; ++q) {
      acc[2 * q]      = __uint_as_float(ua[q] << 16);
      acc[2 * q + 1]  = __uint_as_float(ua[q] & 0xffff0000u);
      acc[8 + 2 * q]     = __uint_as_float(ub[q] << 16);
      acc[8 + 2 * q + 1] = __uint_as_float(ub[q] & 0xffff0000u);
    }
  }
  int s = rowstart[node], c = cnt[node];
  int j = 0;
  for (; j + 4 <= c; j += 4) {
    int idx[4];
#pragma unroll
    for (int u = 0; u < 4; ++u) idx[u] = csr[s + j + u];
    uint4 va[4], vb[4];
#pragma unroll
    for (int u = 0; u < 4; ++u) {
      va[u] = U[(size_t)idx[u] * 8 + kh];
      vb[u] = U[(size_t)idx[u] * 8 + 4 + kh];
    }
#pragma unroll
    for (int u = 0; u < 4; ++u) {
      uint_t a0 = va[u].x, a1 = va[u].y, a2 = va[u].z, a3 = va[u].w;
      uint_t b0 = vb[u].x, b1 = vb[u].y, b2 = vb[u].z, b3 = vb[u].w;
      acc[0] += __uint_as_float(a0 << 16); acc[1] += __uint_as_float(a0 & 0xffff0000u);
      acc[2] += __uint_as_float(a1 << 16); acc[3] += __uint_as_float(a1 & 0xffff0000u);
      acc[4] += __uint_as_float(a2 << 16); acc[5] += __uint_as_float(a2 & 0xffff0000u);
      acc[6] += __uint_as_float(a3 << 16); acc[7] += __uint_as_float(a3 & 0xffff0000u);
      acc[8]  += __uint_as_float(b0 << 16); acc[9]  += __uint_as_float(b0 & 0xffff0000u);
      acc[10] += __uint_as_float(b1 << 16); acc[11] += __uint_as_float(b1 & 0xffff0000u);
      acc[12] += __uint_as_float(b2 << 16); acc[13] += __uint_as_float(b2 & 0xffff0000u);
      acc[14] += __uint_as_float(b3 << 16); acc[15] += __uint_as_float(b3 & 0xffff0000u);
    }
  }
  for (; j < c; ++j) {
    int sn = csr[s + j];
    uint4 a = U[(size_t)sn * 8 + kh];
    uint4 b = U[(size_t)sn * 8 + 4 + kh];
    uint_t a0 = a.x, a1 = a.y, a2 = a.z, a3 = a.w;
    uint_t b0 = b.x, b1 = b.y, b2 = b.z, b3 = b.w;
    acc[0] += __uint_as_float(a0 << 16); acc[1] += __uint_as_float(a0 & 0xffff0000u);
    acc[2] += __uint_as_float(a1 << 16); acc[3] += __uint_as_float(a1 & 0xffff0000u);
    acc[4] += __uint_as_float(a2 << 16); acc[5] += __uint_as_float(a2 & 0xffff0000u);
    acc[6] += __uint_as_float(a3 << 16); acc[7] += __uint_as_float(a3 & 0xffff0000u);
    acc[8]  += __uint_as_float(b0 << 16); acc[9]  += __uint_as_float(b0 & 0xffff0000u);
    acc[10] += __uint_as_float(b1 << 16); acc[11] += __uint_as_float(b1 & 0xffff0000u);
    acc[12] += __uint_as_float(b2 << 16); acc[13] += __uint_as_float(b2 & 0xffff0000u);
    acc[14] += __uint_as_float(b3 << 16); acc[15] += __uint_as_float(b3 & 0xffff0000u);
  }

  const float dv = dinv[node];
  u16x8 pav, pbv;
#pragma unroll
  for (int q = 0; q < 8; ++q) {
    pav[q] = f2bf(fmaxf(acc[q] * dv + bias[kh * 8 + q], 0.0f));
    pbv[q] = f2bf(fmaxf(acc[8 + q] * dv + bias[32 + kh * 8 + q], 0.0f));
  }
  const bf16x8 pa = (bf16x8)pav, pb = (bf16x8)pbv;

  f32x4 gac[4];
  const f32x4 zz = {0.f, 0.f, 0.f, 0.f};
#pragma unroll
  for (int ct = 0; ct < 4; ++ct) gac[ct] = zz;
#pragma unroll
  for (int ct = 0; ct < 4; ++ct) {
    const int n = ct * 16 + lr;
    const int bb0 = (n * 128 + kh * 16) ^ ((n & 7) << 4);
    const int bb1 = (n * 128 + 64 + kh * 16) ^ ((n & 7) << 4);
    bf16x8 bh0 = *(const bf16x8*)&Wh[bb0 >> 1];
    bf16x8 bl0 = *(const bf16x8*)&Wl_[bb0 >> 1];
    bf16x8 bh1 = *(const bf16x8*)&Wh[bb1 >> 1];
    bf16x8 bl1 = *(const bf16x8*)&Wl_[bb1 >> 1];
    gac[ct] = __builtin_amdgcn_mfma_f32_16x16x32_bf16(pa, bl0, gac[ct], 0, 0, 0);
    gac[ct] = __builtin_amdgcn_mfma_f32_16x16x32_bf16(pa, bh0, gac[ct], 0, 0, 0);
    gac[ct] = __builtin_amdgcn_mfma_f32_16x16x32_bf16(pb, bl1, gac[ct], 0, 0, 0);
    gac[ct] = __builtin_amdgcn_mfma_f32_16x16x32_bf16(pb, bh1, gac[ct], 0, 0, 0);
  }

#pragma unroll
  for (int r = 0; r < 4; ++r) {
    int oslot = slot0 + kh * 4 + r;
    if (oslot < NN) {
      int onode = perm[NN - 1 - oslot];
      float odv = dinv[onode];
#pragma unroll
      for (int ct = 0; ct < 4; ++ct) {
        int col = ct * 16 + lr;
        float v = gac[ct][r] * odv + bf2f(hc[(size_t)onode * 64 + col]);
        Un[(size_t)onode * 64 + col] = f2bf(v);
      }
    }
  }
}

// ---------------- aggregation (final only): out f32 = sigmoid(acc*dinv + bc) ----------------

template <int D, int MODE>
__global__ __launch_bounds__(256) void agg_k(const uint4* __restrict__ t, const int* __restrict__ perm,
                                             const int* __restrict__ rowstart, const int* __restrict__ cnt,
                                             const int* __restrict__ csr, const float* __restrict__ dinv,
                                             const float* __restrict__ bias, void* __restrict__ outv) {
  constexpr int LPN = D / 8;
  int slot = blockIdx.x * (256 / LPN) + threadIdx.x / LPN;
  int lane = threadIdx.x % LPN;
  if (slot >= NN) return;
  int node = perm[NN - 1 - slot];

  float acc[8];
  uint4 sv = t[(size_t)node * LPN + lane];
  {
    uint_t u[4] = {sv.x, sv.y, sv.z, sv.w};
#pragma unroll
    for (int q = 0; q < 4; ++q) {
      acc[2 * q]     = __uint_as_float(u[q] << 16);
      acc[2 * q + 1] = __uint_as_float(u[q] & 0xffff0000u);
    }
  }
  int s = rowstart[node], c = cnt[node];
  int j = 0;
  for (; j + 8 <= c; j += 8) {
    int idx[8];
#pragma unroll
    for (int u = 0; u < 8; ++u) idx[u] = csr[s + j + u];
    uint4 v[8];
#pragma unroll
    for (int u = 0; u < 8; ++u) v[u] = t[(size_t)idx[u] * LPN + lane];
#pragma unroll
    for (int u = 0; u < 8; ++u) {
      uint_t q0 = v[u].x, q1 = v[u].y, q2 = v[u].z, q3 = v[u].w;
      acc[0] += __uint_as_float(q0 << 16); acc[1] += __uint_as_float(q0 & 0xffff0000u);
      acc[2] += __uint_as_float(q1 << 16); acc[3] += __uint_as_float(q1 & 0xffff0000u);
      acc[4] += __uint_as_float(q2 << 16); acc[5] += __uint_as_float(q2 & 0xffff0000u);
      acc[6] += __uint_as_float(q3 << 16); acc[7] += __uint_as_float(q3 & 0xffff0000u);
    }
  }
  for (; j < c; ++j) {
    int sn = csr[s + j];
    uint4 v = t[(size_t)sn * LPN + lane];
    uint_t q0 = v.x, q1 = v.y, q2 = v.z, q3 = v.w;
    acc[0] += __uint_as_float(q0 << 16); acc[1] += __uint_as_float(q0 & 0xffff0000u);
    acc[2] += __uint_as_float(q1 << 16); acc[3] += __uint_as_float(q1 & 0xffff0000u);
    acc[4] += __uint_as_float(q2 << 16); acc[5] += __uint_as_float(q2 & 0xffff0000u);
    acc[6] += __uint_as_float(q3 << 16); acc[7] += __uint_as_float(q3 & 0xffff0000u);
  }
  float dv = dinv[node];
  if constexpr (MODE == 0) {
    u16x8 ov;
#pragma unroll
    for (int q = 0; q < 8; ++q) {
      float o = fmaxf(acc[q] * dv + bias[lane * 8 + q], 0.0f);
      ov[q] = f2bf(o);
    }
    *(u16x8*)&((ushort_t*)outv)[(size_t)node * D + lane * 8] = ov;
  } else {
    float o[8];
#pragma unroll
    for (int q = 0; q < 8; ++q) {
      float v2 = acc[q] * dv + bias[lane * 8 + q];
      o[q] = 1.0f / (1.0f + __expf(-v2));
    }
    float4 o0 = {o[0], o[1], o[2], o[3]};
    float4 o1 = {o[4], o[5], o[6], o[7]};
    float* outf = (float*)outv;
    *(float4*)&outf[(size_t)node * D + lane * 8] = o0;
    *(float4*)&outf[(size_t)node * D + lane * 8 + 4] = o1;
  }
}

// ---------------- launch ----------------

extern "C" void kernel_launch(void* const* d_in, const int* in_sizes, int n_in,
                              void* d_out, int out_size, void* d_ws, size_t ws_size,
                              hipStream_t stream) {
  const float* x  = (const float*)d_in[0];
  const float* y  = (const float*)d_in[1];
  const int* ei   = (const int*)d_in[2];
  const float* Wg1 = (const float*)d_in[3];
  const float* bg1 = (const float*)d_in[4];
  const float* Wg2 = (const float*)d_in[5];
  const float* bg2 = (const float*)d_in[6];   // folded into bc
  const float* Wl  = (const float*)d_in[7];
  const float* bl  = (const float*)d_in[8];
  const float* Wf  = (const float*)d_in[9];
  const float* bf  = (const float*)d_in[10];
  float* out = (float*)d_out;

  char* ws = (char*)d_ws;
  size_t off = 0;
  auto alloc = [&](size_t bytes) { void* p = ws + off; off += (bytes + 511) & ~(size_t)511; return p; };
  int* cnt      = (int*)alloc((size_t)NN * 4);
  int* rowstart = (int*)alloc((size_t)NN * 4);
  int* blocksum = (int*)alloc(512);
  float* dinv   = (float*)alloc((size_t)NN * 4);
  int* csr      = (int*)alloc((size_t)NE * 4);
  int* bcnt     = (int*)alloc((size_t)NB * 4);   // 3128 -> 3584
  int* dbin     = (int*)alloc(DBINS * 4);        // adjacent: one memset covers both (4096 B)
  uint_t* pairs = (uint_t*)alloc((size_t)NB * BCAP * 4);
  int* perm     = (int*)alloc((size_t)NN * 4);
  int* dcur     = (int*)alloc(DBINS * 4);
  ushort_t* Tb  = (ushort_t*)alloc((size_t)NN * 128 * 2);  // conv1 staging; halves = U ping/pong later
  ushort_t* Ub  = (ushort_t*)alloc((size_t)NN * 64 * 2);   // hc buffer
  ushort_t* G1h = (ushort_t*)alloc(128 * 128 * 2);
  ushort_t* G1l = (ushort_t*)alloc(128 * 128 * 2);
  ushort_t* Lh  = (ushort_t*)alloc(10 * 64 * 64 * 2);
  ushort_t* Ll  = (ushort_t*)alloc(10 * 64 * 64 * 2);
  ushort_t* Fh  = (ushort_t*)alloc(64 * 192 * 2);          // composed tail weight (k-major)
  ushort_t* Fl  = (ushort_t*)alloc(64 * 192 * 2);
  float* bc     = (float*)alloc(64 * 4);                   // composed tail bias
  ushort_t* uA = Tb;                     // U ping (Tb dead after fcv)
  ushort_t* uB = Tb + (size_t)NN * 64;   // U pong

  const int* esrc = ei;
  const int* edst = ei + NE;

  wcprep_k<<<272, 256, 0, stream>>>(Wg1, Wl, Wg2, Wf, bg2, bl + (size_t)9 * 64, bf,
                                    G1h, G1l, Lh, Ll, Fh, Fl, bc);
  hipMemsetAsync(bcnt, 0, 4096, stream);   // covers bcnt + dbin (adjacent allocs)
  bucketA_k<<<BKBLK, 512, 0, stream>>>(esrc, edst, bcnt, pairs);
  count2_k<<<NB, 256, 0, stream>>>(bcnt, pairs, cnt, dinv, dbin);
  scan1<<<98, 1024, 0, stream>>>(cnt, rowstart, blocksum);
  scan2<<<1, 1, 0, stream>>>(blocksum, 98, dbin, dcur);
  scan3<<<98, 1024, 0, stream>>>(rowstart, blocksum);
  fillplace_k<<<NB + (NN + 255) / 256, 256, 0, stream>>>(bcnt, pairs, rowstart, csr, cnt, dcur, perm);

  const int GG = (NN + 63) / 64;

  // feature conv1 GEMM, then fused conv1-agg + Wc1 projection -> hc
  mgemm_k<128, 128><<<GG, 256, 0, stream>>>(x, G1h, G1l, dinv, Tb);
  fcv_k<<<GG, 256, 0, stream>>>((const uint4*)Tb, Fh, Fl, perm, rowstart, cnt, csr,
                                dinv, bg1, Ub);

  // label chain: U0 = dinv.*(y W0); 8 fused layers; fused tail adds hc
  mgemmW_k<64, 0, 64, true><<<GG, 256, 0, stream>>>(y, nullptr, Lh, Ll, dinv, uA);
  const ushort_t* uin = uA;
  for (int j = 0; j < 8; ++j) {
    ushort_t* uout = (j & 1) ? uA : uB;
    flay_k<<<GG, 256, 0, stream>>>((const uint4*)uin, Lh + (size_t)(j + 1) * 4096, Ll + (size_t)(j + 1) * 4096,
                                   perm, rowstart, cnt, csr, dinv, bl + (size_t)j * 64, uout);
    uin = uout;
  }
  // uin = U8 (in uA); ftail: uB = hc + dinv.*(relu(dinv*agg(U8)+b8) @ Wc2)
  ftail_k<<<GG, 256, 0, stream>>>((const uint4*)uin, Fh, Fl, perm, rowstart, cnt, csr,
                                  dinv, bl + (size_t)8 * 64, Ub, uB);

  // final: out = sigmoid(S(uB) + bc)
  agg_k<64, 1><<<NN / 32, 256, 0, stream>>>((const uint4*)uB, perm, rowstart, cnt, csr, dinv, bc, out);
}